// Round 5
// baseline (8279.690 us; speedup 1.0000x reference)
//
#include <hip/hip_runtime.h>
#include <hip/hip_bf16.h>

#define NN 1024
#define HD 64
#define EPSV 1e-5f
#define BIGINF 1e5f

__device__ __forceinline__ float siluf(float v) { return v / (1.0f + __expf(-v)); }
__device__ __forceinline__ float pnorm(float dx, float dy, float dz) {
    return sqrtf(dx * dx + dy * dy + dz * dz + EPSV);
}
__device__ __forceinline__ float wsum(float v) {
#pragma unroll
    for (int off = 32; off > 0; off >>= 1) v += __shfl_xor(v, off, 64);
    return v;
}

// ---- kT: transpose weight mats so per-output rows are contiguous (s_load) ----
__global__ void kT(const float* __restrict__ ew2, const float* __restrict__ cw1,
                   const float* __restrict__ fw1, float* __restrict__ ew2T,
                   float* __restrict__ cw1T, float* __restrict__ fw1T) {
    const int o = blockIdx.x, k = threadIdx.x;
    ew2T[o * 64 + k] = ew2[k * 64 + o];
    cw1T[o * 64 + k] = cw1[k * 64 + o];
    fw1T[o * 64 + k] = fw1[k * 64 + o];
}

// ---- kA: HA = h@ew1[0:64]; HBT = (h@ew1[64:128] + eb1)^T  [k][j] layout ----
__global__ void kA(const float* __restrict__ h, const float* __restrict__ ew1,
                   const float* __restrict__ eb1, float* __restrict__ HA,
                   float* __restrict__ HBT) {
    const int i = blockIdx.x, o = threadIdx.x;
    float hv = h[i * HD + o];
    float a = 0.f, b = eb1[o];
#pragma unroll
    for (int k = 0; k < HD; k++) {
        float hk = __shfl(hv, k, 64);
        a += hk * ew1[k * HD + o];
        b += hk * ew1[(HD + k) * HD + o];
    }
    HA[i * HD + o] = a;
    HBT[o * NN + i] = b;
}

// helper: compute he[64] for pair (i block, j lane) — scalar-operand GEMV
#define HE_COMPUTE(he, HAi, HBT, w1, eb2, ew2T, nrm, j)                        \
    _Pragma("unroll") for (int o = 0; o < 64; o++) he[o] = eb2[o];             \
    _Pragma("unroll") for (int kc = 0; kc < 64; kc += 16) {                    \
        float u[16];                                                           \
        _Pragma("unroll") for (int t = 0; t < 16; t++) {                       \
            int k = kc + t;                                                    \
            u[t] = siluf(HAi[k] + HBT[k * NN + j] + nrm * w1[k]);              \
        }                                                                      \
        _Pragma("unroll") for (int o = 0; o < 64; o++) {                       \
            float s0 = 0.f, s1 = 0.f, s2 = 0.f, s3 = 0.f;                      \
            _Pragma("unroll") for (int t = 0; t < 16; t += 4) {                \
                s0 += u[t + 0] * ew2T[o * 64 + kc + t + 0];                    \
                s1 += u[t + 1] * ew2T[o * 64 + kc + t + 1];                    \
                s2 += u[t + 2] * ew2T[o * 64 + kc + t + 2];                    \
                s3 += u[t + 3] * ew2T[o * 64 + kc + t + 3];                    \
            }                                                                  \
            he[o] += (s0 + s1) + (s2 + s3);                                    \
        }                                                                      \
    }

// ---- kB: pass 1 — h_e, semantic logits ls, phi -> xupd.  lanes = j. ----
__global__ __launch_bounds__(256, 2) void kB(
    const float* __restrict__ x, const float* __restrict__ ew1,
    const float* __restrict__ ew2T, const float* __restrict__ eb2,
    const float* __restrict__ cw1T, const float* __restrict__ cb1,
    const float* __restrict__ cw2, const float* __restrict__ aw,
    const float* __restrict__ ab, const float* __restrict__ HA,
    const float* __restrict__ HBT, float* __restrict__ ls,
    float* __restrict__ xupd) {
    const int lane = threadIdx.x & 63;
    const int jc = threadIdx.x >> 6;  // 4 waves = 4 j-chunks, same i
    const int i = blockIdx.x;
    const float* HAi = HA + i * 64;        // uniform -> s_load
    const float* w1 = ew1 + 128 * 64;      // uniform
    const float xi0 = x[i * 3 + 0], xi1 = x[i * 3 + 1], xi2 = x[i * 3 + 2];
    const float ab0 = ab[0];
    float xa0 = 0.f, xa1 = 0.f, xa2 = 0.f;

#pragma unroll 1
    for (int t4 = 0; t4 < 4; ++t4) {
        const int j = jc * 256 + t4 * 64 + lane;
        float dx = xi0 - x[j * 3 + 0];
        float dy = xi1 - x[j * 3 + 1];
        float dz = xi2 - x[j * 3 + 2];
        float nrm = pnorm(dx, dy, dz);

        float he[64];
        HE_COMPUTE(he, HAi, HBT, w1, eb2, ew2T, nrm, j)

        // semantic logit (per-lane full dot, scalar aw)
        float v0 = 0.f, v1 = 0.f, v2 = 0.f, v3 = 0.f;
#pragma unroll
        for (int o = 0; o < 64; o += 4) {
            v0 += he[o + 0] * aw[o + 0];
            v1 += he[o + 1] * aw[o + 1];
            v2 += he[o + 2] * aw[o + 2];
            v3 += he[o + 3] * aw[o + 3];
        }
        float sv = (v0 + v1) + (v2 + v3) + ab0;
        sv = sv >= 0.f ? sv : 0.01f * sv;
        if (j == i) sv -= BIGINF;
        ls[(size_t)i * NN + j] = sv;  // coalesced over lanes

        // phi = silu(h_e @ cw1 + cb1) . cw2
        float ph = 0.f;
#pragma unroll
        for (int o2 = 0; o2 < 64; o2++) {
            float p0 = 0.f, p1 = 0.f, p2 = 0.f, p3 = 0.f;
#pragma unroll
            for (int o = 0; o < 64; o += 4) {
                p0 += he[o + 0] * cw1T[o2 * 64 + o + 0];
                p1 += he[o + 1] * cw1T[o2 * 64 + o + 1];
                p2 += he[o + 2] * cw1T[o2 * 64 + o + 2];
                p3 += he[o + 3] * cw1T[o2 * 64 + o + 3];
            }
            float p = cb1[o2] + (p0 + p1) + (p2 + p3);
            ph += siluf(p) * cw2[o2];
        }
        xa0 += dx * ph;
        xa1 += dy * ph;
        xa2 += dz * ph;
    }
    xa0 = wsum(xa0);
    xa1 = wsum(xa1);
    xa2 = wsum(xa2);
    if (lane == 0) {
        atomicAdd(&xupd[i * 3 + 0], xa0);
        atomicAdd(&xupd[i * 3 + 1], xa1);
        atomicAdd(&xupd[i * 3 + 2], xa2);
    }
}

// ---- kC: per-row softmax stats -> rowm = m_e+m_s, rowd = S + EPS*Ze*Zs ----
__global__ void kC(const float* __restrict__ x, const float* __restrict__ lg,
                   const float* __restrict__ ls, float* __restrict__ rowm,
                   float* __restrict__ rowd) {
    const int i = blockIdx.x;
    const int t = threadIdx.x;  // 256 threads
    const float gamma = __expf(lg[0]);
    const float xi0 = x[i * 3 + 0], xi1 = x[i * 3 + 1], xi2 = x[i * 3 + 2];
    float le[4], lv[4];
    float me = -3.0e38f, ms = -3.0e38f;
#pragma unroll
    for (int q = 0; q < 4; q++) {
        int j = t + q * 256;
        float dx = xi0 - x[j * 3 + 0];
        float dy = xi1 - x[j * 3 + 1];
        float dz = xi2 - x[j * 3 + 2];
        float nrm = pnorm(dx, dy, dz);
        float l = -(nrm + (i == j ? BIGINF : 0.f)) * gamma;
        le[q] = l;
        lv[q] = ls[(size_t)i * NN + j];
        me = fmaxf(me, l);
        ms = fmaxf(ms, lv[q]);
    }
    __shared__ float sm[4], ss[4], s1[4], s2[4], s3[4];
#pragma unroll
    for (int off = 32; off > 0; off >>= 1) {
        me = fmaxf(me, __shfl_xor(me, off, 64));
        ms = fmaxf(ms, __shfl_xor(ms, off, 64));
    }
    const int w = t >> 6;
    if ((t & 63) == 0) { sm[w] = me; ss[w] = ms; }
    __syncthreads();
    me = fmaxf(fmaxf(sm[0], sm[1]), fmaxf(sm[2], sm[3]));
    ms = fmaxf(fmaxf(ss[0], ss[1]), fmaxf(ss[2], ss[3]));
    float Se = 0.f, Ss = 0.f, Sq = 0.f;
#pragma unroll
    for (int q = 0; q < 4; q++) {
        float ee = __expf(le[q] - me);
        float es = __expf(lv[q] - ms);
        Se += ee; Ss += es; Sq += ee * es;
    }
    Se = wsum(Se); Ss = wsum(Ss); Sq = wsum(Sq);
    if ((t & 63) == 0) { s1[w] = Se; s2[w] = Ss; s3[w] = Sq; }
    __syncthreads();
    if (t == 0) {
        float Te = s1[0] + s1[1] + s1[2] + s1[3];
        float Ts = s2[0] + s2[1] + s2[2] + s2[3];
        float Tq = s3[0] + s3[1] + s3[2] + s3[3];
        rowm[i] = me + ms;
        rowd[i] = Tq + EPSV * Te * Ts;
    }
}

// ---- kD: pass 2 — comb, h_agg, coeff -> combos.  lanes = j. ----
__global__ __launch_bounds__(256, 2) void kD(
    const float* __restrict__ x, const float* __restrict__ ew1,
    const float* __restrict__ ew2T, const float* __restrict__ eb2,
    const float* __restrict__ fw1T, const float* __restrict__ fb1,
    const float* __restrict__ fw2, const float* __restrict__ fb2,
    const float* __restrict__ lg, const float* __restrict__ HA,
    const float* __restrict__ HBT, const float* __restrict__ ls,
    const float* __restrict__ rowm, const float* __restrict__ rowd,
    float* __restrict__ hagg, float* __restrict__ combos) {
    const int lane = threadIdx.x & 63;
    const int jc = threadIdx.x >> 6;
    const int i = blockIdx.x;
    const float* HAi = HA + i * 64;
    const float* w1 = ew1 + 128 * 64;
    const float gamma = __expf(lg[0]);
    const float rm = rowm[i];
    const float invd = 1.0f / rowd[i];
    const float xi0 = x[i * 3 + 0], xi1 = x[i * 3 + 1], xi2 = x[i * 3 + 2];

    float haccL[64];
#pragma unroll
    for (int o = 0; o < 64; o++) haccL[o] = 0.f;
    float cr0 = 0.f, cr1 = 0.f;  // combos idx = lane, 64+lane

#pragma unroll 1
    for (int t4 = 0; t4 < 4; ++t4) {
        const int j = jc * 256 + t4 * 64 + lane;
        float dx = xi0 - x[j * 3 + 0];
        float dy = xi1 - x[j * 3 + 1];
        float dz = xi2 - x[j * 3 + 2];
        float nrm = pnorm(dx, dy, dz);

        float he[64];
        HE_COMPUTE(he, HAi, HBT, w1, eb2, ew2T, nrm, j)

        float lsv = ls[(size_t)i * NN + j];
        float le = -(nrm + (j == i ? BIGINF : 0.f)) * gamma;
        float comb = __expf(le + lsv - rm) * invd;
#pragma unroll
        for (int o = 0; o < 64; o++) haccL[o] += he[o] * comb;

        // V = h_e @ fw1; wv = silu(comb*V + fb1); coeff = wv @ fw2 + fb2
        float cAcc[32];
#pragma unroll
        for (int c = 0; c < 32; c++) cAcc[c] = 0.f;
#pragma unroll
        for (int o2 = 0; o2 < 64; o2++) {
            float p0 = 0.f, p1 = 0.f, p2 = 0.f, p3 = 0.f;
#pragma unroll
            for (int o = 0; o < 64; o += 4) {
                p0 += he[o + 0] * fw1T[o2 * 64 + o + 0];
                p1 += he[o + 1] * fw1T[o2 * 64 + o + 1];
                p2 += he[o + 2] * fw1T[o2 * 64 + o + 2];
                p3 += he[o + 3] * fw1T[o2 * 64 + o + 3];
            }
            float V = (p0 + p1) + (p2 + p3);
            float wv = siluf(comb * V + fb1[o2]);
#pragma unroll
            for (int c = 0; c < 32; c++) cAcc[c] += wv * fw2[o2 * 32 + c];
        }
        float inv1 = 1.0f / (nrm + 1.0f);
        float fx = dx * inv1, fy = dy * inv1, fz = dz * inv1;
#pragma unroll
        for (int c = 0; c < 32; c++) {
            float cf = cAcc[c] + fb2[c];
            float q0 = wsum(cf * fx);
            float q1 = wsum(cf * fy);
            float q2 = wsum(cf * fz);
            const int i0 = c * 3, i1 = c * 3 + 1, i2 = c * 3 + 2;
            cr0 += (lane == i0) ? q0 : 0.f;
            cr1 += (lane + 64 == i0) ? q0 : 0.f;
            cr0 += (lane == i1) ? q1 : 0.f;
            cr1 += (lane + 64 == i1) ? q1 : 0.f;
            cr0 += (lane == i2) ? q2 : 0.f;
            cr1 += (lane + 64 == i2) ? q2 : 0.f;
        }
    }
    // hagg: reduce haccL across lanes, one output per lane
    float hr = 0.f;
#pragma unroll
    for (int o = 0; o < 64; o++) {
        float s = wsum(haccL[o]);
        hr = (lane == o) ? s : hr;
    }
    atomicAdd(&hagg[i * 64 + lane], hr);
    atomicAdd(&combos[i * 96 + lane], cr0);
    if (lane < 32) atomicAdd(&combos[i * 96 + 64 + lane], cr1);
}

// ---- kE: post MLPs + node update + coordinate output (fp32 out) ----
__global__ void kE(const float* __restrict__ h, const float* __restrict__ x,
                   const float* __restrict__ nw1, const float* __restrict__ nb1,
                   const float* __restrict__ nw2, const float* __restrict__ nb2,
                   const float* __restrict__ pw1, const float* __restrict__ pb1,
                   const float* __restrict__ pw2, const float* __restrict__ pb2,
                   const float* __restrict__ hagg, const float* __restrict__ combos,
                   const float* __restrict__ xupd, float* __restrict__ out) {
    const int i = blockIdx.x, o = threadIdx.x;
    const float invN = 1.0f / (float)NN;
    float r = 0.f;
    if (o < 32) {
        float v0 = combos[i * 96 + o * 3 + 0] * invN;
        float v1 = combos[i * 96 + o * 3 + 1] * invN;
        float v2 = combos[i * 96 + o * 3 + 2] * invN;
        r = v0 * v0 + v1 * v1 + v2 * v2;
    }
    float t1 = pb1[o];
#pragma unroll
    for (int k = 0; k < 32; k++) t1 += __shfl(r, k, 64) * pw1[k * 64 + o];
    t1 = siluf(t1);
    float hc = pb2[o];
#pragma unroll
    for (int k = 0; k < 64; k++) hc += __shfl(t1, k, 64) * pw2[k * 64 + o];
    float hi = h[i * 64 + o];
    float ha = hagg[i * 64 + o];
    float t2 = nb1[o];
#pragma unroll
    for (int k = 0; k < 64; k++) t2 += __shfl(hi, k, 64) * nw1[k * 64 + o];
#pragma unroll
    for (int k = 0; k < 64; k++) t2 += __shfl(ha, k, 64) * nw1[(64 + k) * 64 + o];
#pragma unroll
    for (int k = 0; k < 64; k++) t2 += __shfl(hc, k, 64) * nw1[(128 + k) * 64 + o];
    t2 = siluf(t2);
    float ho = hi + nb2[o];
#pragma unroll
    for (int k = 0; k < 64; k++) ho += __shfl(t2, k, 64) * nw2[k * 64 + o];
    out[i * 64 + o] = ho;
    if (o < 3)
        out[NN * 64 + i * 3 + o] = x[i * 3 + o] + xupd[i * 3 + o] * invN;
}

extern "C" void kernel_launch(void* const* d_in, const int* in_sizes, int n_in,
                              void* d_out, int out_size, void* d_ws, size_t ws_size,
                              hipStream_t stream) {
    (void)in_sizes; (void)n_in; (void)out_size; (void)ws_size;
    const float* h   = (const float*)d_in[0];
    const float* x   = (const float*)d_in[1];
    const float* ew1 = (const float*)d_in[2];
    const float* eb1 = (const float*)d_in[3];
    const float* ew2 = (const float*)d_in[4];
    const float* eb2 = (const float*)d_in[5];
    const float* nw1 = (const float*)d_in[6];
    const float* nb1 = (const float*)d_in[7];
    const float* nw2 = (const float*)d_in[8];
    const float* nb2 = (const float*)d_in[9];
    const float* cw1 = (const float*)d_in[10];
    const float* cb1 = (const float*)d_in[11];
    const float* cw2 = (const float*)d_in[12];
    const float* aw  = (const float*)d_in[13];
    const float* ab  = (const float*)d_in[14];
    const float* fw1 = (const float*)d_in[15];
    const float* fb1 = (const float*)d_in[16];
    const float* fw2 = (const float*)d_in[17];
    const float* fb2 = (const float*)d_in[18];
    const float* pw1 = (const float*)d_in[19];
    const float* pb1 = (const float*)d_in[20];
    const float* pw2 = (const float*)d_in[21];
    const float* pb2 = (const float*)d_in[22];
    const float* lg  = (const float*)d_in[23];
    float* out = (float*)d_out;

    float* W      = (float*)d_ws;
    float* ls     = W;                        // N*N
    float* HA     = ls + (size_t)NN * NN;     // N*64
    float* HBT    = HA + NN * 64;             // 64*N (transposed)
    float* rowm   = HBT + NN * 64;            // N
    float* rowd   = rowm + NN;                // N
    float* hagg   = rowd + NN;                // N*64   (atomic acc)
    float* combos = hagg + NN * 64;           // N*96   (atomic acc)
    float* xupd   = combos + NN * 96;         // N*3    (atomic acc)
    float* ew2T   = xupd + NN * 3;            // 64*64
    float* cw1T   = ew2T + 64 * 64;           // 64*64
    float* fw1T   = cw1T + 64 * 64;           // 64*64

    hipMemsetAsync(hagg, 0, (size_t)(NN * 64 + NN * 96 + NN * 3) * sizeof(float), stream);
    kT<<<64, 64, 0, stream>>>(ew2, cw1, fw1, ew2T, cw1T, fw1T);
    kA<<<NN, 64, 0, stream>>>(h, ew1, eb1, HA, HBT);
    kB<<<NN, 256, 0, stream>>>(x, ew1, ew2T, eb2, cw1T, cb1, cw2, aw, ab, HA, HBT, ls, xupd);
    kC<<<NN, 256, 0, stream>>>(x, lg, ls, rowm, rowd);
    kD<<<NN, 256, 0, stream>>>(x, ew1, ew2T, eb2, fw1T, fb1, fw2, fb2, lg, HA, HBT, ls,
                               rowm, rowd, hagg, combos);
    kE<<<NN, 64, 0, stream>>>(h, x, nw1, nb1, nw2, nb2, pw1, pb1, pw2, pb2,
                              hagg, combos, xupd, out);
}

// Round 6
// 837.300 us; speedup vs baseline: 9.8886x; 9.8886x over previous
//
#include <hip/hip_runtime.h>
#include <hip/hip_bf16.h>

#define NN 1024
#define HD 64
#define PAD 68
#define EPSV 1e-5f
#define BIGINF 1e5f

__device__ __forceinline__ float siluf(float v) { return v / (1.0f + __expf(-v)); }
__device__ __forceinline__ float pnorm(float dx, float dy, float dz) {
    return sqrtf(dx * dx + dy * dy + dz * dz + EPSV);
}
__device__ __forceinline__ float wsum(float v) {
#pragma unroll
    for (int off = 32; off > 0; off >>= 1) v += __shfl_xor(v, off, 64);
    return v;
}

// ---- kA: HA[i][k] = h@ew1[0:64]; HBT[k][j] = (h@ew1[64:128] + eb1)^T ----
__global__ void kA(const float* __restrict__ h, const float* __restrict__ ew1,
                   const float* __restrict__ eb1, float* __restrict__ HA,
                   float* __restrict__ HBT) {
    const int i = blockIdx.x, o = threadIdx.x;
    float hv = h[i * HD + o];
    float a = 0.f, b = eb1[o];
#pragma unroll
    for (int k = 0; k < HD; k++) {
        float hk = __shfl(hv, k, 64);
        a += hk * ew1[k * HD + o];
        b += hk * ew1[(HD + k) * HD + o];
    }
    HA[i * HD + o] = a;
    HBT[o * NN + i] = b;
}

// ---- kB: per (i, j-tile): U, he-GEMM, sv, phi-GEMM, xupd ----
__global__ __launch_bounds__(256, 3) void kB(
    const float* __restrict__ x, const float* __restrict__ ew1,
    const float* __restrict__ ew2, const float* __restrict__ eb2,
    const float* __restrict__ cw1, const float* __restrict__ cb1,
    const float* __restrict__ cw2, const float* __restrict__ aw,
    const float* __restrict__ ab, const float* __restrict__ HA,
    const float* __restrict__ HBT, float* __restrict__ ls,
    float* __restrict__ xupd) {
    __shared__ float sUT[64 * PAD];   // U^T [k][j]
    __shared__ float sHeT[64 * PAD];  // he^T [o][j]
    __shared__ float sW[64 * 64];     // staged weights (ew2 then cw1)
    __shared__ float sNrm[64], sDx[64], sDy[64], sDz[64], sPh[64], sAw[64], sSv[64];

    const int tid = threadIdx.x;
    const int i = blockIdx.x;
    const int jbase = blockIdx.y * 64;
    const int ty = tid >> 4, tx = tid & 15;

    // phase0: distances + aw + zero sSv; stage ew2
    if (tid < 64) {
        int j = jbase + tid;
        float dx = x[i * 3 + 0] - x[j * 3 + 0];
        float dy = x[i * 3 + 1] - x[j * 3 + 1];
        float dz = x[i * 3 + 2] - x[j * 3 + 2];
        sNrm[tid] = pnorm(dx, dy, dz);
        sDx[tid] = dx; sDy[tid] = dy; sDz[tid] = dz;
        sAw[tid] = aw[tid];
        sSv[tid] = 0.f;
    }
#pragma unroll
    for (int q = 0; q < 4; q++)
        ((float4*)sW)[q * 256 + tid] = ((const float4*)ew2)[q * 256 + tid];
    __syncthreads();

    // phase1: U staging (U^T[k][j])
    {
        const int k = tid & 63;
        const float HAk = HA[i * 64 + k];
        const float w1k = ew1[128 * 64 + k];
#pragma unroll
        for (int q = 0; q < 4; q++) {
            int j0 = ((tid >> 6) + q * 4) * 4;
            float4 hb = *(const float4*)&HBT[k * NN + jbase + j0];
            float4 nr = *(const float4*)&sNrm[j0];
            float4 u;
            u.x = siluf(HAk + hb.x + nr.x * w1k);
            u.y = siluf(HAk + hb.y + nr.y * w1k);
            u.z = siluf(HAk + hb.z + nr.z * w1k);
            u.w = siluf(HAk + hb.w + nr.w * w1k);
            *(float4*)&sUT[k * PAD + j0] = u;
        }
    }
    __syncthreads();

    // GEMM1: he[j][o] = U@ew2 + eb2   (j0=4ty, o0=4tx)
    float c[4][4] = {};
#pragma unroll 8
    for (int k = 0; k < 64; k++) {
        float4 a = *(float4*)&sUT[k * PAD + ty * 4];
        float4 b = *(float4*)&sW[k * 64 + tx * 4];
        c[0][0] += a.x * b.x; c[0][1] += a.x * b.y; c[0][2] += a.x * b.z; c[0][3] += a.x * b.w;
        c[1][0] += a.y * b.x; c[1][1] += a.y * b.y; c[1][2] += a.y * b.z; c[1][3] += a.y * b.w;
        c[2][0] += a.z * b.x; c[2][1] += a.z * b.y; c[2][2] += a.z * b.z; c[2][3] += a.z * b.w;
        c[3][0] += a.w * b.x; c[3][1] += a.w * b.y; c[3][2] += a.w * b.z; c[3][3] += a.w * b.w;
    }
    {
        float4 e = *(const float4*)&eb2[tx * 4];
        float eb[4] = {e.x, e.y, e.z, e.w};
#pragma unroll
        for (int n = 0; n < 4; n++) {
            float4 v = {c[0][n] + eb[n], c[1][n] + eb[n], c[2][n] + eb[n], c[3][n] + eb[n]};
            *(float4*)&sHeT[(tx * 4 + n) * PAD + ty * 4] = v;
        }
    }
    __syncthreads();

    // restage sW = cw1; sv partials (he . aw)
#pragma unroll
    for (int q = 0; q < 4; q++)
        ((float4*)sW)[q * 256 + tid] = ((const float4*)cw1)[q * 256 + tid];
    {
        const int j = tid & 63, g = tid >> 6;
        float s = 0.f;
#pragma unroll
        for (int t = 0; t < 16; t++) {
            int o = g * 16 + t;
            s += sHeT[o * PAD + j] * sAw[o];
        }
        atomicAdd(&sSv[j], s);
    }
    __syncthreads();

    // GEMM2: P[j][o2] = he@cw1
    float p[4][4] = {};
#pragma unroll 8
    for (int o = 0; o < 64; o++) {
        float4 a = *(float4*)&sHeT[o * PAD + ty * 4];
        float4 b = *(float4*)&sW[o * 64 + tx * 4];
        p[0][0] += a.x * b.x; p[0][1] += a.x * b.y; p[0][2] += a.x * b.z; p[0][3] += a.x * b.w;
        p[1][0] += a.y * b.x; p[1][1] += a.y * b.y; p[1][2] += a.y * b.z; p[1][3] += a.y * b.w;
        p[2][0] += a.z * b.x; p[2][1] += a.z * b.y; p[2][2] += a.z * b.z; p[2][3] += a.z * b.w;
        p[3][0] += a.w * b.x; p[3][1] += a.w * b.y; p[3][2] += a.w * b.z; p[3][3] += a.w * b.w;
    }
    {
        float4 cb = *(const float4*)&cb1[tx * 4];
        float4 cw = *(const float4*)&cw2[tx * 4];
        float cbv[4] = {cb.x, cb.y, cb.z, cb.w};
        float cwv[4] = {cw.x, cw.y, cw.z, cw.w};
#pragma unroll
        for (int m = 0; m < 4; m++) {
            float ph = 0.f;
#pragma unroll
            for (int n = 0; n < 4; n++) ph += siluf(p[m][n] + cbv[n]) * cwv[n];
#pragma unroll
            for (int off = 1; off < 16; off <<= 1) ph += __shfl_xor(ph, off, 64);
            if (tx == 0) sPh[ty * 4 + m] = ph;
        }
    }
    __syncthreads();

    // finalize: ls write + xupd
    if (tid < 64) {
        float s = sSv[tid] + ab[0];
        s = s >= 0.f ? s : 0.01f * s;
        if (jbase + tid == i) s -= BIGINF;
        ls[(size_t)i * NN + jbase + tid] = s;
        float xa0 = wsum(sPh[tid] * sDx[tid]);
        float xa1 = wsum(sPh[tid] * sDy[tid]);
        float xa2 = wsum(sPh[tid] * sDz[tid]);
        if (tid == 0) {
            atomicAdd(&xupd[i * 3 + 0], xa0);
            atomicAdd(&xupd[i * 3 + 1], xa1);
            atomicAdd(&xupd[i * 3 + 2], xa2);
        }
    }
}

// ---- kC: per-row softmax stats (unchanged, verified) ----
__global__ void kC(const float* __restrict__ x, const float* __restrict__ lg,
                   const float* __restrict__ ls, float* __restrict__ rowm,
                   float* __restrict__ rowd) {
    const int i = blockIdx.x;
    const int t = threadIdx.x;
    const float gamma = __expf(lg[0]);
    const float xi0 = x[i * 3 + 0], xi1 = x[i * 3 + 1], xi2 = x[i * 3 + 2];
    float le[4], lv[4];
    float me = -3.0e38f, ms = -3.0e38f;
#pragma unroll
    for (int q = 0; q < 4; q++) {
        int j = t + q * 256;
        float dx = xi0 - x[j * 3 + 0];
        float dy = xi1 - x[j * 3 + 1];
        float dz = xi2 - x[j * 3 + 2];
        float nrm = pnorm(dx, dy, dz);
        float l = -(nrm + (i == j ? BIGINF : 0.f)) * gamma;
        le[q] = l;
        lv[q] = ls[(size_t)i * NN + j];
        me = fmaxf(me, l);
        ms = fmaxf(ms, lv[q]);
    }
    __shared__ float sm[4], ss[4], s1[4], s2[4], s3[4];
#pragma unroll
    for (int off = 32; off > 0; off >>= 1) {
        me = fmaxf(me, __shfl_xor(me, off, 64));
        ms = fmaxf(ms, __shfl_xor(ms, off, 64));
    }
    const int w = t >> 6;
    if ((t & 63) == 0) { sm[w] = me; ss[w] = ms; }
    __syncthreads();
    me = fmaxf(fmaxf(sm[0], sm[1]), fmaxf(sm[2], sm[3]));
    ms = fmaxf(fmaxf(ss[0], ss[1]), fmaxf(ss[2], ss[3]));
    float Se = 0.f, Ss = 0.f, Sq = 0.f;
#pragma unroll
    for (int q = 0; q < 4; q++) {
        float ee = __expf(le[q] - me);
        float es = __expf(lv[q] - ms);
        Se += ee; Ss += es; Sq += ee * es;
    }
    Se = wsum(Se); Ss = wsum(Ss); Sq = wsum(Sq);
    if ((t & 63) == 0) { s1[w] = Se; s2[w] = Ss; s3[w] = Sq; }
    __syncthreads();
    if (t == 0) {
        rowm[i] = me + ms;
        rowd[i] = (s3[0] + s3[1] + s3[2] + s3[3]) +
                  EPSV * (s1[0] + s1[1] + s1[2] + s1[3]) * (s2[0] + s2[1] + s2[2] + s2[3]);
    }
}

// ---- kD: per (i, j-tile): U, he-GEMM, comb, hagg, V-GEMM, coeff-GEMM, combos ----
__global__ __launch_bounds__(256, 3) void kD(
    const float* __restrict__ x, const float* __restrict__ ew1,
    const float* __restrict__ ew2, const float* __restrict__ eb2,
    const float* __restrict__ fw1, const float* __restrict__ fb1,
    const float* __restrict__ fw2, const float* __restrict__ fb2,
    const float* __restrict__ lg, const float* __restrict__ HA,
    const float* __restrict__ HBT, const float* __restrict__ ls,
    const float* __restrict__ rowm, const float* __restrict__ rowd,
    float* __restrict__ hagg, float* __restrict__ combos) {
    __shared__ float sUT[64 * PAD];   // U^T, later wv^T
    __shared__ float sHeT[64 * PAD];  // he^T
    __shared__ float sW[64 * 64];     // ew2 -> fw1 -> fw2
    __shared__ float sNrm[64], sFx[64], sFy[64], sFz[64], sComb[64], sHag[64];
    __shared__ float sCombos[96];

    const int tid = threadIdx.x;
    const int i = blockIdx.x;
    const int jbase = blockIdx.y * 64;
    const int ty = tid >> 4, tx = tid & 15;

    // phase0: distances, comb, zero accumulators; stage ew2
    if (tid < 64) {
        int j = jbase + tid;
        float dx = x[i * 3 + 0] - x[j * 3 + 0];
        float dy = x[i * 3 + 1] - x[j * 3 + 1];
        float dz = x[i * 3 + 2] - x[j * 3 + 2];
        float nrm = pnorm(dx, dy, dz);
        float inv1 = 1.0f / (nrm + 1.0f);
        sNrm[tid] = nrm;
        sFx[tid] = dx * inv1; sFy[tid] = dy * inv1; sFz[tid] = dz * inv1;
        float gamma = __expf(lg[0]);
        float le = -(nrm + (j == i ? BIGINF : 0.f)) * gamma;
        float lsv = ls[(size_t)i * NN + j];
        sComb[tid] = __expf(le + lsv - rowm[i]) / rowd[i];
        sHag[tid] = 0.f;
    } else if (tid < 160) {
        sCombos[tid - 64] = 0.f;
    }
#pragma unroll
    for (int q = 0; q < 4; q++)
        ((float4*)sW)[q * 256 + tid] = ((const float4*)ew2)[q * 256 + tid];
    __syncthreads();

    // phase1: U staging
    {
        const int k = tid & 63;
        const float HAk = HA[i * 64 + k];
        const float w1k = ew1[128 * 64 + k];
#pragma unroll
        for (int q = 0; q < 4; q++) {
            int j0 = ((tid >> 6) + q * 4) * 4;
            float4 hb = *(const float4*)&HBT[k * NN + jbase + j0];
            float4 nr = *(const float4*)&sNrm[j0];
            float4 u;
            u.x = siluf(HAk + hb.x + nr.x * w1k);
            u.y = siluf(HAk + hb.y + nr.y * w1k);
            u.z = siluf(HAk + hb.z + nr.z * w1k);
            u.w = siluf(HAk + hb.w + nr.w * w1k);
            *(float4*)&sUT[k * PAD + j0] = u;
        }
    }
    __syncthreads();

    // GEMM1: he = U@ew2 + eb2
    float c[4][4] = {};
#pragma unroll 8
    for (int k = 0; k < 64; k++) {
        float4 a = *(float4*)&sUT[k * PAD + ty * 4];
        float4 b = *(float4*)&sW[k * 64 + tx * 4];
        c[0][0] += a.x * b.x; c[0][1] += a.x * b.y; c[0][2] += a.x * b.z; c[0][3] += a.x * b.w;
        c[1][0] += a.y * b.x; c[1][1] += a.y * b.y; c[1][2] += a.y * b.z; c[1][3] += a.y * b.w;
        c[2][0] += a.z * b.x; c[2][1] += a.z * b.y; c[2][2] += a.z * b.z; c[2][3] += a.z * b.w;
        c[3][0] += a.w * b.x; c[3][1] += a.w * b.y; c[3][2] += a.w * b.z; c[3][3] += a.w * b.w;
    }
    {
        float4 e = *(const float4*)&eb2[tx * 4];
        float eb[4] = {e.x, e.y, e.z, e.w};
#pragma unroll
        for (int n = 0; n < 4; n++) {
            float4 v = {c[0][n] + eb[n], c[1][n] + eb[n], c[2][n] + eb[n], c[3][n] + eb[n]};
            *(float4*)&sHeT[(tx * 4 + n) * PAD + ty * 4] = v;
        }
    }
    __syncthreads();

    // restage sW = fw1; hagg partials (he[j][o]*comb[j])
#pragma unroll
    for (int q = 0; q < 4; q++)
        ((float4*)sW)[q * 256 + tid] = ((const float4*)fw1)[q * 256 + tid];
    {
        const int o = tid & 63, g = tid >> 6;
        float s = 0.f;
#pragma unroll
        for (int t = 0; t < 16; t++) {
            int j = g * 16 + t;
            s += sHeT[o * PAD + j] * sComb[j];
        }
        atomicAdd(&sHag[o], s);
    }
    __syncthreads();

    // GEMM-V: V = he@fw1; wv = silu(comb*V + fb1) -> sUT as wv^T
    float v[4][4] = {};
#pragma unroll 8
    for (int o = 0; o < 64; o++) {
        float4 a = *(float4*)&sHeT[o * PAD + ty * 4];
        float4 b = *(float4*)&sW[o * 64 + tx * 4];
        v[0][0] += a.x * b.x; v[0][1] += a.x * b.y; v[0][2] += a.x * b.z; v[0][3] += a.x * b.w;
        v[1][0] += a.y * b.x; v[1][1] += a.y * b.y; v[1][2] += a.y * b.z; v[1][3] += a.y * b.w;
        v[2][0] += a.z * b.x; v[2][1] += a.z * b.y; v[2][2] += a.z * b.z; v[2][3] += a.z * b.w;
        v[3][0] += a.w * b.x; v[3][1] += a.w * b.y; v[3][2] += a.w * b.z; v[3][3] += a.w * b.w;
    }
    {
        float4 fb = *(const float4*)&fb1[tx * 4];
        float fbv[4] = {fb.x, fb.y, fb.z, fb.w};
        float4 cm = *(const float4*)&sComb[ty * 4];
        float cmv[4] = {cm.x, cm.y, cm.z, cm.w};
#pragma unroll
        for (int n = 0; n < 4; n++) {
            float4 w;
            w.x = siluf(cmv[0] * v[0][n] + fbv[n]);
            w.y = siluf(cmv[1] * v[1][n] + fbv[n]);
            w.z = siluf(cmv[2] * v[2][n] + fbv[n]);
            w.w = siluf(cmv[3] * v[3][n] + fbv[n]);
            *(float4*)&sUT[(tx * 4 + n) * PAD + ty * 4] = w;
        }
    }
    __syncthreads();

    // restage sW = fw2 (64x32)
#pragma unroll
    for (int q = 0; q < 2; q++)
        ((float4*)sW)[q * 256 + tid] = ((const float4*)fw2)[q * 256 + tid];
    __syncthreads();

    // GEMM-C: coeff[j][c] = wv@fw2 + fb2; combos += coeff^T @ dirs
    {
        const int c0 = tx * 2;
        float c2[4][2] = {};
#pragma unroll 8
        for (int o2 = 0; o2 < 64; o2++) {
            float4 a = *(float4*)&sUT[o2 * PAD + ty * 4];
            float b0 = sW[o2 * 32 + c0], b1 = sW[o2 * 32 + c0 + 1];
            c2[0][0] += a.x * b0; c2[0][1] += a.x * b1;
            c2[1][0] += a.y * b0; c2[1][1] += a.y * b1;
            c2[2][0] += a.z * b0; c2[2][1] += a.z * b1;
            c2[3][0] += a.w * b0; c2[3][1] += a.w * b1;
        }
        float px0 = 0.f, py0 = 0.f, pz0 = 0.f, px1 = 0.f, py1 = 0.f, pz1 = 0.f;
        const float fb20 = fb2[c0], fb21 = fb2[c0 + 1];
#pragma unroll
        for (int m = 0; m < 4; m++) {
            int j = ty * 4 + m;
            float cf0 = c2[m][0] + fb20, cf1 = c2[m][1] + fb21;
            px0 += cf0 * sFx[j]; py0 += cf0 * sFy[j]; pz0 += cf0 * sFz[j];
            px1 += cf1 * sFx[j]; py1 += cf1 * sFy[j]; pz1 += cf1 * sFz[j];
        }
        atomicAdd(&sCombos[c0 * 3 + 0], px0);
        atomicAdd(&sCombos[c0 * 3 + 1], py0);
        atomicAdd(&sCombos[c0 * 3 + 2], pz0);
        atomicAdd(&sCombos[c0 * 3 + 3], px1);
        atomicAdd(&sCombos[c0 * 3 + 4], py1);
        atomicAdd(&sCombos[c0 * 3 + 5], pz1);
    }
    __syncthreads();

    if (tid < 64) atomicAdd(&hagg[i * 64 + tid], sHag[tid]);
    if (tid < 96) atomicAdd(&combos[i * 96 + tid], sCombos[tid]);
}

// ---- kE: post MLPs + node update + coordinate output (unchanged, verified) ----
__global__ void kE(const float* __restrict__ h, const float* __restrict__ x,
                   const float* __restrict__ nw1, const float* __restrict__ nb1,
                   const float* __restrict__ nw2, const float* __restrict__ nb2,
                   const float* __restrict__ pw1, const float* __restrict__ pb1,
                   const float* __restrict__ pw2, const float* __restrict__ pb2,
                   const float* __restrict__ hagg, const float* __restrict__ combos,
                   const float* __restrict__ xupd, float* __restrict__ out) {
    const int i = blockIdx.x, o = threadIdx.x;
    const float invN = 1.0f / (float)NN;
    float r = 0.f;
    if (o < 32) {
        float v0 = combos[i * 96 + o * 3 + 0] * invN;
        float v1 = combos[i * 96 + o * 3 + 1] * invN;
        float v2 = combos[i * 96 + o * 3 + 2] * invN;
        r = v0 * v0 + v1 * v1 + v2 * v2;
    }
    float t1 = pb1[o];
#pragma unroll
    for (int k = 0; k < 32; k++) t1 += __shfl(r, k, 64) * pw1[k * 64 + o];
    t1 = siluf(t1);
    float hc = pb2[o];
#pragma unroll
    for (int k = 0; k < 64; k++) hc += __shfl(t1, k, 64) * pw2[k * 64 + o];
    float hi = h[i * 64 + o];
    float ha = hagg[i * 64 + o];
    float t2 = nb1[o];
#pragma unroll
    for (int k = 0; k < 64; k++) t2 += __shfl(hi, k, 64) * nw1[k * 64 + o];
#pragma unroll
    for (int k = 0; k < 64; k++) t2 += __shfl(ha, k, 64) * nw1[(64 + k) * 64 + o];
#pragma unroll
    for (int k = 0; k < 64; k++) t2 += __shfl(hc, k, 64) * nw1[(128 + k) * 64 + o];
    t2 = siluf(t2);
    float ho = hi + nb2[o];
#pragma unroll
    for (int k = 0; k < 64; k++) ho += __shfl(t2, k, 64) * nw2[k * 64 + o];
    out[i * 64 + o] = ho;
    if (o < 3)
        out[NN * 64 + i * 3 + o] = x[i * 3 + o] + xupd[i * 3 + o] * invN;
}

extern "C" void kernel_launch(void* const* d_in, const int* in_sizes, int n_in,
                              void* d_out, int out_size, void* d_ws, size_t ws_size,
                              hipStream_t stream) {
    (void)in_sizes; (void)n_in; (void)out_size; (void)ws_size;
    const float* h   = (const float*)d_in[0];
    const float* x   = (const float*)d_in[1];
    const float* ew1 = (const float*)d_in[2];
    const float* eb1 = (const float*)d_in[3];
    const float* ew2 = (const float*)d_in[4];
    const float* eb2 = (const float*)d_in[5];
    const float* nw1 = (const float*)d_in[6];
    const float* nb1 = (const float*)d_in[7];
    const float* nw2 = (const float*)d_in[8];
    const float* nb2 = (const float*)d_in[9];
    const float* cw1 = (const float*)d_in[10];
    const float* cb1 = (const float*)d_in[11];
    const float* cw2 = (const float*)d_in[12];
    const float* aw  = (const float*)d_in[13];
    const float* ab  = (const float*)d_in[14];
    const float* fw1 = (const float*)d_in[15];
    const float* fb1 = (const float*)d_in[16];
    const float* fw2 = (const float*)d_in[17];
    const float* fb2 = (const float*)d_in[18];
    const float* pw1 = (const float*)d_in[19];
    const float* pb1 = (const float*)d_in[20];
    const float* pw2 = (const float*)d_in[21];
    const float* pb2 = (const float*)d_in[22];
    const float* lg  = (const float*)d_in[23];
    float* out = (float*)d_out;

    float* W      = (float*)d_ws;
    float* ls     = W;                        // N*N
    float* HA     = ls + (size_t)NN * NN;     // N*64
    float* HBT    = HA + NN * 64;             // 64*N
    float* rowm   = HBT + NN * 64;            // N
    float* rowd   = rowm + NN;                // N
    float* hagg   = rowd + NN;                // N*64   (atomic acc)
    float* combos = hagg + NN * 64;           // N*96   (atomic acc)
    float* xupd   = combos + NN * 96;         // N*3    (atomic acc)

    hipMemsetAsync(hagg, 0, (size_t)(NN * 64 + NN * 96 + NN * 3) * sizeof(float), stream);
    kA<<<NN, 64, 0, stream>>>(h, ew1, eb1, HA, HBT);
    dim3 g2(NN, NN / 64);
    kB<<<g2, 256, 0, stream>>>(x, ew1, ew2, eb2, cw1, cb1, cw2, aw, ab, HA, HBT, ls, xupd);
    kC<<<NN, 256, 0, stream>>>(x, lg, ls, rowm, rowd);
    kD<<<g2, 256, 0, stream>>>(x, ew1, ew2, eb2, fw1, fb1, fw2, fb2, lg, HA, HBT, ls,
                               rowm, rowd, hagg, combos);
    kE<<<NN, 64, 0, stream>>>(h, x, nw1, nb1, nw2, nb2, pw1, pb1, pw2, pb2,
                              hagg, combos, xupd, out);
}

// Round 7
// 374.963 us; speedup vs baseline: 22.0813x; 2.2330x over previous
//
#include <hip/hip_runtime.h>
#include <hip/hip_bf16.h>

#define NN 1024
#define LSTR 72  // bf16 row stride (2-way bank aliasing only)
#define EPSV 1e-5f
#define BIGINF 1e5f

typedef __attribute__((ext_vector_type(8))) short short8;
typedef __attribute__((ext_vector_type(4))) short short4v;
typedef __attribute__((ext_vector_type(4))) float f32x4;

__device__ __forceinline__ float siluf(float v) { return v / (1.0f + __expf(-v)); }
__device__ __forceinline__ float pnorm(float dx, float dy, float dz) {
    return sqrtf(dx * dx + dy * dy + dz * dz + EPSV);
}
__device__ __forceinline__ float wsum(float v) {
#pragma unroll
    for (int off = 32; off > 0; off >>= 1) v += __shfl_xor(v, off, 64);
    return v;
}
__device__ __forceinline__ float red16(float v) {  // reduce over 16-lane col group
    v += __shfl_xor(v, 1, 64); v += __shfl_xor(v, 2, 64);
    v += __shfl_xor(v, 4, 64); v += __shfl_xor(v, 8, 64);
    return v;
}
__device__ __forceinline__ float redquad(float v) {  // reduce across 4 quads
    v += __shfl_xor(v, 16, 64); v += __shfl_xor(v, 32, 64);
    return v;
}
__device__ __forceinline__ short f2bs(float v) {
    __hip_bfloat16 b = __float2bfloat16(v);
    return *reinterpret_cast<short*>(&b);
}

// ---- kT: bf16 transposed weights BT[n][k] for MFMA B-operands ----
__global__ void kT(const float* __restrict__ ew2, const float* __restrict__ cw1,
                   const float* __restrict__ fw1, const float* __restrict__ fw2,
                   short* __restrict__ ew2T, short* __restrict__ cw1T,
                   short* __restrict__ fw1T, short* __restrict__ fw2T) {
    const int o = blockIdx.x, k = threadIdx.x;
    ew2T[o * 64 + k] = f2bs(ew2[k * 64 + o]);
    cw1T[o * 64 + k] = f2bs(cw1[k * 64 + o]);
    fw1T[o * 64 + k] = f2bs(fw1[k * 64 + o]);
    if (o < 32) fw2T[o * 64 + k] = f2bs(fw2[k * 32 + o]);
}

// ---- kA: HA[i][k], HB[j][k] (both row-major) ----
__global__ void kA(const float* __restrict__ h, const float* __restrict__ ew1,
                   const float* __restrict__ eb1, float* __restrict__ HA,
                   float* __restrict__ HB) {
    const int i = blockIdx.x, o = threadIdx.x;
    float hv = h[i * 64 + o];
    float a = 0.f, b = eb1[o];
#pragma unroll
    for (int k = 0; k < 64; k++) {
        float hk = __shfl(hv, k, 64);
        a += hk * ew1[k * 64 + o];
        b += hk * ew1[(64 + k) * 64 + o];
    }
    HA[i * 64 + o] = a;
    HB[i * 64 + o] = b;
}

// stage 64-wide bf16 weight rows (global) into LDS stride-LSTR
__device__ __forceinline__ void stageW(const short* __restrict__ g, short* s,
                                       int tid, int rows) {
    for (int c = tid; c < rows * 16; c += 256) {
        int r = c >> 4, q = c & 15;
        *(short4v*)&s[r * LSTR + q * 4] = *(const short4v*)&g[r * 64 + q * 4];
    }
}

// 64x64x64 bf16 MFMA GEMM: wave w does rows w*16..+16, 4 N-blocks
__device__ __forceinline__ void gemm64(const short* sA, const short* sB, int w,
                                       int col, int quad, f32x4 acc[4]) {
    const short* ap = &sA[(w * 16 + col) * LSTR + quad * 8];
#pragma unroll
    for (int kb = 0; kb < 2; kb++) {
        short8 a = *(const short8*)&ap[kb * 32];
#pragma unroll
        for (int nb = 0; nb < 4; nb++) {
            short8 b = *(const short8*)&sB[(nb * 16 + col) * LSTR + kb * 32 + quad * 8];
            acc[nb] = __builtin_amdgcn_mfma_f32_16x16x32_bf16(a, b, acc[nb], 0, 0, 0);
        }
    }
}

// ---- kB: pass 1 — he-GEMM, sv -> ls, phi-GEMM -> xupd ----
__global__ __launch_bounds__(256) void kB(
    const float* __restrict__ x, const float* __restrict__ ew1,
    const float* __restrict__ eb2, const float* __restrict__ cb1,
    const float* __restrict__ cw2, const float* __restrict__ aw,
    const float* __restrict__ ab, const float* __restrict__ HA,
    const float* __restrict__ HB, const short* __restrict__ ew2T,
    const short* __restrict__ cw1T, float* __restrict__ ls,
    float* __restrict__ xupd) {
    __shared__ __align__(16) short sU[64 * LSTR];
    __shared__ __align__(16) short sHe[64 * LSTR];
    __shared__ __align__(16) short sW[64 * LSTR];
    __shared__ float sNrm[64], sDx[64], sDy[64], sDz[64], sSv[64], sPh[64];

    const int tid = threadIdx.x;
    const int i = blockIdx.x;
    const int jbase = blockIdx.y * 64;
    const int lane = tid & 63, w = tid >> 6;
    const int col = lane & 15, quad = lane >> 4;

    if (tid < 64) {
        int j = jbase + tid;
        float dx = x[i * 3 + 0] - x[j * 3 + 0];
        float dy = x[i * 3 + 1] - x[j * 3 + 1];
        float dz = x[i * 3 + 2] - x[j * 3 + 2];
        sNrm[tid] = pnorm(dx, dy, dz);
        sDx[tid] = dx; sDy[tid] = dy; sDz[tid] = dz;
    }
    stageW(ew2T, sW, tid, 64);
    __syncthreads();

    // U staging: u = silu(HA[i,k] + HB[j,k] + nrm_j*w1[k]) -> bf16 rows [j][k]
    {
        int j = tid >> 2, kc = (tid & 3) * 16;
        float nrm = sNrm[j];
        const float* hb = &HB[(jbase + j) * 64 + kc];
        const float* ha = &HA[i * 64 + kc];
        const float* w1 = &ew1[128 * 64 + kc];
        short8 v0, v1;
#pragma unroll
        for (int t = 0; t < 8; t++) v0[t] = f2bs(siluf(ha[t] + hb[t] + nrm * w1[t]));
#pragma unroll
        for (int t = 0; t < 8; t++) v1[t] = f2bs(siluf(ha[8 + t] + hb[8 + t] + nrm * w1[8 + t]));
        *(short8*)&sU[j * LSTR + kc] = v0;
        *(short8*)&sU[j * LSTR + kc + 8] = v1;
    }
    __syncthreads();

    // GEMM1: he = U@ew2 + eb2; write bf16 rows; sv partials
    f32x4 acc[4] = {{0.f, 0.f, 0.f, 0.f}, {0.f, 0.f, 0.f, 0.f},
                    {0.f, 0.f, 0.f, 0.f}, {0.f, 0.f, 0.f, 0.f}};
    gemm64(sU, sW, w, col, quad, acc);
    {
        float eb[4], awv[4];
#pragma unroll
        for (int nb = 0; nb < 4; nb++) { eb[nb] = eb2[nb * 16 + col]; awv[nb] = aw[nb * 16 + col]; }
#pragma unroll
        for (int reg = 0; reg < 4; reg++) {
            int row = w * 16 + quad * 4 + reg;
            float sv = 0.f;
#pragma unroll
            for (int nb = 0; nb < 4; nb++) {
                float he = acc[nb][reg] + eb[nb];
                sHe[row * LSTR + nb * 16 + col] = f2bs(he);
                sv += he * awv[nb];
            }
            sv = red16(sv);
            if (col == 0) sSv[row] = sv;
        }
    }
    __syncthreads();
    if (tid < 64) {
        float s = sSv[tid] + ab[0];
        s = s >= 0.f ? s : 0.01f * s;
        if (jbase + tid == i) s -= BIGINF;
        ls[(size_t)i * NN + jbase + tid] = s;
    }
    stageW(cw1T, sW, tid, 64);
    __syncthreads();

    // GEMM2: P = he@cw1; phi = sum silu(P+cb1)*cw2
    f32x4 p[4] = {{0.f, 0.f, 0.f, 0.f}, {0.f, 0.f, 0.f, 0.f},
                  {0.f, 0.f, 0.f, 0.f}, {0.f, 0.f, 0.f, 0.f}};
    gemm64(sHe, sW, w, col, quad, p);
    {
        float cbv[4], cwv[4];
#pragma unroll
        for (int nb = 0; nb < 4; nb++) { cbv[nb] = cb1[nb * 16 + col]; cwv[nb] = cw2[nb * 16 + col]; }
#pragma unroll
        for (int reg = 0; reg < 4; reg++) {
            float ph = 0.f;
#pragma unroll
            for (int nb = 0; nb < 4; nb++) ph += siluf(p[nb][reg] + cbv[nb]) * cwv[nb];
            ph = red16(ph);
            if (col == 0) sPh[w * 16 + quad * 4 + reg] = ph;
        }
    }
    __syncthreads();
    if (tid < 64) {
        float xa0 = wsum(sPh[tid] * sDx[tid]);
        float xa1 = wsum(sPh[tid] * sDy[tid]);
        float xa2 = wsum(sPh[tid] * sDz[tid]);
        if (tid == 0) {
            atomicAdd(&xupd[i * 3 + 0], xa0);
            atomicAdd(&xupd[i * 3 + 1], xa1);
            atomicAdd(&xupd[i * 3 + 2], xa2);
        }
    }
}

// ---- kC: per-row softmax stats (verified) ----
__global__ void kC(const float* __restrict__ x, const float* __restrict__ lg,
                   const float* __restrict__ ls, float* __restrict__ rowm,
                   float* __restrict__ rowd) {
    const int i = blockIdx.x;
    const int t = threadIdx.x;
    const float gamma = __expf(lg[0]);
    const float xi0 = x[i * 3 + 0], xi1 = x[i * 3 + 1], xi2 = x[i * 3 + 2];
    float le[4], lv[4];
    float me = -3.0e38f, ms = -3.0e38f;
#pragma unroll
    for (int q = 0; q < 4; q++) {
        int j = t + q * 256;
        float dx = xi0 - x[j * 3 + 0];
        float dy = xi1 - x[j * 3 + 1];
        float dz = xi2 - x[j * 3 + 2];
        float nrm = pnorm(dx, dy, dz);
        float l = -(nrm + (i == j ? BIGINF : 0.f)) * gamma;
        le[q] = l;
        lv[q] = ls[(size_t)i * NN + j];
        me = fmaxf(me, l);
        ms = fmaxf(ms, lv[q]);
    }
    __shared__ float sm[4], ss[4], s1[4], s2[4], s3[4];
#pragma unroll
    for (int off = 32; off > 0; off >>= 1) {
        me = fmaxf(me, __shfl_xor(me, off, 64));
        ms = fmaxf(ms, __shfl_xor(ms, off, 64));
    }
    const int w = t >> 6;
    if ((t & 63) == 0) { sm[w] = me; ss[w] = ms; }
    __syncthreads();
    me = fmaxf(fmaxf(sm[0], sm[1]), fmaxf(sm[2], sm[3]));
    ms = fmaxf(fmaxf(ss[0], ss[1]), fmaxf(ss[2], ss[3]));
    float Se = 0.f, Ss = 0.f, Sq = 0.f;
#pragma unroll
    for (int q = 0; q < 4; q++) {
        float ee = __expf(le[q] - me);
        float es = __expf(lv[q] - ms);
        Se += ee; Ss += es; Sq += ee * es;
    }
    Se = wsum(Se); Ss = wsum(Ss); Sq = wsum(Sq);
    if ((t & 63) == 0) { s1[w] = Se; s2[w] = Ss; s3[w] = Sq; }
    __syncthreads();
    if (t == 0) {
        rowm[i] = me + ms;
        rowd[i] = (s3[0] + s3[1] + s3[2] + s3[3]) +
                  EPSV * (s1[0] + s1[1] + s1[2] + s1[3]) * (s2[0] + s2[1] + s2[2] + s2[3]);
    }
}

// ---- kD: pass 2 — he-GEMM, hagg, V-GEMM, coeff-GEMM -> combos ----
__global__ __launch_bounds__(256) void kD(
    const float* __restrict__ x, const float* __restrict__ ew1,
    const float* __restrict__ eb2, const float* __restrict__ fb1,
    const float* __restrict__ fb2, const float* __restrict__ lg,
    const float* __restrict__ HA, const float* __restrict__ HB,
    const short* __restrict__ ew2T, const short* __restrict__ fw1T,
    const short* __restrict__ fw2T, const float* __restrict__ ls,
    const float* __restrict__ rowm, const float* __restrict__ rowd,
    float* __restrict__ hagg, float* __restrict__ combos) {
    __shared__ __align__(16) short sU[64 * LSTR];  // U, then wv
    __shared__ __align__(16) short sHe[64 * LSTR];
    __shared__ __align__(16) short sW[64 * LSTR];
    __shared__ float sNrm[64], sFx[64], sFy[64], sFz[64], sComb[64], sHag[64], sCombos[96];

    const int tid = threadIdx.x;
    const int i = blockIdx.x;
    const int jbase = blockIdx.y * 64;
    const int lane = tid & 63, w = tid >> 6;
    const int col = lane & 15, quad = lane >> 4;

    if (tid < 64) {
        int j = jbase + tid;
        float dx = x[i * 3 + 0] - x[j * 3 + 0];
        float dy = x[i * 3 + 1] - x[j * 3 + 1];
        float dz = x[i * 3 + 2] - x[j * 3 + 2];
        float nrm = pnorm(dx, dy, dz);
        float inv1 = 1.0f / (nrm + 1.0f);
        sNrm[tid] = nrm;
        sFx[tid] = dx * inv1; sFy[tid] = dy * inv1; sFz[tid] = dz * inv1;
        float gamma = __expf(lg[0]);
        float le = -(nrm + (j == i ? BIGINF : 0.f)) * gamma;
        sComb[tid] = __expf(le + ls[(size_t)i * NN + j] - rowm[i]) / rowd[i];
        sHag[tid] = 0.f;
    } else if (tid < 160) {
        sCombos[tid - 64] = 0.f;
    }
    stageW(ew2T, sW, tid, 64);
    __syncthreads();

    {
        int j = tid >> 2, kc = (tid & 3) * 16;
        float nrm = sNrm[j];
        const float* hb = &HB[(jbase + j) * 64 + kc];
        const float* ha = &HA[i * 64 + kc];
        const float* w1 = &ew1[128 * 64 + kc];
        short8 v0, v1;
#pragma unroll
        for (int t = 0; t < 8; t++) v0[t] = f2bs(siluf(ha[t] + hb[t] + nrm * w1[t]));
#pragma unroll
        for (int t = 0; t < 8; t++) v1[t] = f2bs(siluf(ha[8 + t] + hb[8 + t] + nrm * w1[8 + t]));
        *(short8*)&sU[j * LSTR + kc] = v0;
        *(short8*)&sU[j * LSTR + kc + 8] = v1;
    }
    __syncthreads();

    // GEMM1: he; hagg partials from frags
    f32x4 acc[4] = {{0.f, 0.f, 0.f, 0.f}, {0.f, 0.f, 0.f, 0.f},
                    {0.f, 0.f, 0.f, 0.f}, {0.f, 0.f, 0.f, 0.f}};
    gemm64(sU, sW, w, col, quad, acc);
    {
        float eb[4];
#pragma unroll
        for (int nb = 0; nb < 4; nb++) eb[nb] = eb2[nb * 16 + col];
        float hv[4][4];
#pragma unroll
        for (int reg = 0; reg < 4; reg++) {
            int row = w * 16 + quad * 4 + reg;
#pragma unroll
            for (int nb = 0; nb < 4; nb++) {
                hv[nb][reg] = acc[nb][reg] + eb[nb];
                sHe[row * LSTR + nb * 16 + col] = f2bs(hv[nb][reg]);
            }
        }
#pragma unroll
        for (int nb = 0; nb < 4; nb++) {
            float v = 0.f;
#pragma unroll
            for (int reg = 0; reg < 4; reg++)
                v += hv[nb][reg] * sComb[w * 16 + quad * 4 + reg];
            v = redquad(v);
            if (quad == 0) atomicAdd(&sHag[nb * 16 + col], v);
        }
    }
    __syncthreads();
    stageW(fw1T, sW, tid, 64);
    __syncthreads();

    // GEMM-V: V = he@fw1; wv = silu(comb*V + fb1) -> sU (bf16)
    f32x4 vacc[4] = {{0.f, 0.f, 0.f, 0.f}, {0.f, 0.f, 0.f, 0.f},
                     {0.f, 0.f, 0.f, 0.f}, {0.f, 0.f, 0.f, 0.f}};
    gemm64(sHe, sW, w, col, quad, vacc);
    {
        float fbv[4];
#pragma unroll
        for (int nb = 0; nb < 4; nb++) fbv[nb] = fb1[nb * 16 + col];
#pragma unroll
        for (int reg = 0; reg < 4; reg++) {
            int row = w * 16 + quad * 4 + reg;
            float cm = sComb[row];
#pragma unroll
            for (int nb = 0; nb < 4; nb++)
                sU[row * LSTR + nb * 16 + col] = f2bs(siluf(cm * vacc[nb][reg] + fbv[nb]));
        }
    }
    __syncthreads();
    stageW(fw2T, sW, tid, 32);
    __syncthreads();

    // GEMM-C: coeff = wv@fw2 + fb2 (N=32); combos += coeff^T @ dirs
    {
        f32x4 cacc[2] = {{0.f, 0.f, 0.f, 0.f}, {0.f, 0.f, 0.f, 0.f}};
        const short* ap = &sU[(w * 16 + col) * LSTR + quad * 8];
#pragma unroll
        for (int kb = 0; kb < 2; kb++) {
            short8 a = *(const short8*)&ap[kb * 32];
#pragma unroll
            for (int nb = 0; nb < 2; nb++) {
                short8 b = *(const short8*)&sW[(nb * 16 + col) * LSTR + kb * 32 + quad * 8];
                cacc[nb] = __builtin_amdgcn_mfma_f32_16x16x32_bf16(a, b, cacc[nb], 0, 0, 0);
            }
        }
#pragma unroll
        for (int nb = 0; nb < 2; nb++) {
            float fb2v = fb2[nb * 16 + col];
            float px = 0.f, py = 0.f, pz = 0.f;
#pragma unroll
            for (int reg = 0; reg < 4; reg++) {
                int row = w * 16 + quad * 4 + reg;
                float cf = cacc[nb][reg] + fb2v;
                px += cf * sFx[row]; py += cf * sFy[row]; pz += cf * sFz[row];
            }
            px = redquad(px); py = redquad(py); pz = redquad(pz);
            if (quad == 0) {
                int c = nb * 16 + col;
                atomicAdd(&sCombos[c * 3 + 0], px);
                atomicAdd(&sCombos[c * 3 + 1], py);
                atomicAdd(&sCombos[c * 3 + 2], pz);
            }
        }
    }
    __syncthreads();
    if (tid < 64) atomicAdd(&hagg[i * 64 + tid], sHag[tid]);
    if (tid < 96) atomicAdd(&combos[i * 96 + tid], sCombos[tid]);
}

// ---- kE: post MLPs + node update + coordinate output (verified) ----
__global__ void kE(const float* __restrict__ h, const float* __restrict__ x,
                   const float* __restrict__ nw1, const float* __restrict__ nb1,
                   const float* __restrict__ nw2, const float* __restrict__ nb2,
                   const float* __restrict__ pw1, const float* __restrict__ pb1,
                   const float* __restrict__ pw2, const float* __restrict__ pb2,
                   const float* __restrict__ hagg, const float* __restrict__ combos,
                   const float* __restrict__ xupd, float* __restrict__ out) {
    const int i = blockIdx.x, o = threadIdx.x;
    const float invN = 1.0f / (float)NN;
    float r = 0.f;
    if (o < 32) {
        float v0 = combos[i * 96 + o * 3 + 0] * invN;
        float v1 = combos[i * 96 + o * 3 + 1] * invN;
        float v2 = combos[i * 96 + o * 3 + 2] * invN;
        r = v0 * v0 + v1 * v1 + v2 * v2;
    }
    float t1 = pb1[o];
#pragma unroll
    for (int k = 0; k < 32; k++) t1 += __shfl(r, k, 64) * pw1[k * 64 + o];
    t1 = siluf(t1);
    float hc = pb2[o];
#pragma unroll
    for (int k = 0; k < 64; k++) hc += __shfl(t1, k, 64) * pw2[k * 64 + o];
    float hi = h[i * 64 + o];
    float ha = hagg[i * 64 + o];
    float t2 = nb1[o];
#pragma unroll
    for (int k = 0; k < 64; k++) t2 += __shfl(hi, k, 64) * nw1[k * 64 + o];
#pragma unroll
    for (int k = 0; k < 64; k++) t2 += __shfl(ha, k, 64) * nw1[(64 + k) * 64 + o];
#pragma unroll
    for (int k = 0; k < 64; k++) t2 += __shfl(hc, k, 64) * nw1[(128 + k) * 64 + o];
    t2 = siluf(t2);
    float ho = hi + nb2[o];
#pragma unroll
    for (int k = 0; k < 64; k++) ho += __shfl(t2, k, 64) * nw2[k * 64 + o];
    out[i * 64 + o] = ho;
    if (o < 3)
        out[NN * 64 + i * 3 + o] = x[i * 3 + o] + xupd[i * 3 + o] * invN;
}

extern "C" void kernel_launch(void* const* d_in, const int* in_sizes, int n_in,
                              void* d_out, int out_size, void* d_ws, size_t ws_size,
                              hipStream_t stream) {
    (void)in_sizes; (void)n_in; (void)out_size; (void)ws_size;
    const float* h   = (const float*)d_in[0];
    const float* x   = (const float*)d_in[1];
    const float* ew1 = (const float*)d_in[2];
    const float* eb1 = (const float*)d_in[3];
    const float* ew2 = (const float*)d_in[4];
    const float* eb2 = (const float*)d_in[5];
    const float* nw1 = (const float*)d_in[6];
    const float* nb1 = (const float*)d_in[7];
    const float* nw2 = (const float*)d_in[8];
    const float* nb2 = (const float*)d_in[9];
    const float* cw1 = (const float*)d_in[10];
    const float* cb1 = (const float*)d_in[11];
    const float* cw2 = (const float*)d_in[12];
    const float* aw  = (const float*)d_in[13];
    const float* ab  = (const float*)d_in[14];
    const float* fw1 = (const float*)d_in[15];
    const float* fb1 = (const float*)d_in[16];
    const float* fw2 = (const float*)d_in[17];
    const float* fb2 = (const float*)d_in[18];
    const float* pw1 = (const float*)d_in[19];
    const float* pb1 = (const float*)d_in[20];
    const float* pw2 = (const float*)d_in[21];
    const float* pb2 = (const float*)d_in[22];
    const float* lg  = (const float*)d_in[23];
    float* out = (float*)d_out;

    float* W      = (float*)d_ws;
    float* ls     = W;                        // N*N
    float* HA     = ls + (size_t)NN * NN;     // N*64
    float* HB     = HA + NN * 64;             // N*64
    float* rowm   = HB + NN * 64;             // N
    float* rowd   = rowm + NN;                // N
    float* hagg   = rowd + NN;                // N*64   (atomic acc)
    float* combos = hagg + NN * 64;           // N*96   (atomic acc)
    float* xupd   = combos + NN * 96;         // N*3    (atomic acc)
    short* ew2T   = (short*)(xupd + NN * 3);  // 64*64 bf16
    short* cw1T   = ew2T + 64 * 64;
    short* fw1T   = cw1T + 64 * 64;
    short* fw2T   = fw1T + 64 * 64;           // 32*64 bf16

    hipMemsetAsync(hagg, 0, (size_t)(NN * 64 + NN * 96 + NN * 3) * sizeof(float), stream);
    kT<<<64, 64, 0, stream>>>(ew2, cw1, fw1, fw2, ew2T, cw1T, fw1T, fw2T);
    kA<<<NN, 64, 0, stream>>>(h, ew1, eb1, HA, HB);
    dim3 g2(NN, NN / 64);
    kB<<<g2, 256, 0, stream>>>(x, ew1, eb2, cb1, cw2, aw, ab, HA, HB, ew2T, cw1T, ls, xupd);
    kC<<<NN, 256, 0, stream>>>(x, lg, ls, rowm, rowd);
    kD<<<g2, 256, 0, stream>>>(x, ew1, eb2, fb1, fb2, lg, HA, HB, ew2T, fw1T, fw2T, ls,
                               rowm, rowd, hagg, combos);
    kE<<<NN, 64, 0, stream>>>(h, x, nw1, nb1, nw2, nb2, pw1, pb1, pw2, pb2,
                              hagg, combos, xupd, out);
}

// Round 8
// 360.171 us; speedup vs baseline: 22.9882x; 1.0411x over previous
//
#include <hip/hip_runtime.h>
#include <hip/hip_bf16.h>

#define NN 1024
#define LSTR 72  // bf16 row stride (2-way bank aliasing only)
#define EPSV 1e-5f
#define BIGINF 1e5f

typedef __attribute__((ext_vector_type(8))) short short8;
typedef __attribute__((ext_vector_type(4))) short short4v;
typedef __attribute__((ext_vector_type(4))) float f32x4;

__device__ __forceinline__ float siluf(float v) { return v / (1.0f + __expf(-v)); }
__device__ __forceinline__ float pnorm(float dx, float dy, float dz) {
    return sqrtf(dx * dx + dy * dy + dz * dz + EPSV);
}
__device__ __forceinline__ float wsum(float v) {
#pragma unroll
    for (int off = 32; off > 0; off >>= 1) v += __shfl_xor(v, off, 64);
    return v;
}
__device__ __forceinline__ float red16(float v) {
    v += __shfl_xor(v, 1, 64); v += __shfl_xor(v, 2, 64);
    v += __shfl_xor(v, 4, 64); v += __shfl_xor(v, 8, 64);
    return v;
}
__device__ __forceinline__ float redquad(float v) {
    v += __shfl_xor(v, 16, 64); v += __shfl_xor(v, 32, 64);
    return v;
}
__device__ __forceinline__ short f2bs(float v) {  // RNE (weights, done once)
    __hip_bfloat16 b = __float2bfloat16(v);
    return *reinterpret_cast<short*>(&b);
}
__device__ __forceinline__ short f2bt(float v) {  // truncate (hot path)
    return (short)(__float_as_uint(v) >> 16);
}

// ---- kT: bf16 transposed weights BT[n][k] for MFMA B-operands ----
__global__ void kT(const float* __restrict__ ew2, const float* __restrict__ cw1,
                   const float* __restrict__ fw1, const float* __restrict__ fw2,
                   short* __restrict__ ew2T, short* __restrict__ cw1T,
                   short* __restrict__ fw1T, short* __restrict__ fw2T) {
    const int o = blockIdx.x, k = threadIdx.x;
    ew2T[o * 64 + k] = f2bs(ew2[k * 64 + o]);
    cw1T[o * 64 + k] = f2bs(cw1[k * 64 + o]);
    fw1T[o * 64 + k] = f2bs(fw1[k * 64 + o]);
    if (o < 32) fw2T[o * 64 + k] = f2bs(fw2[k * 32 + o]);
}

// ---- kP: wsv = ew2@aw (sv is linear in he!), svb = eb2.aw + ab ----
__global__ void kP(const float* __restrict__ ew2, const float* __restrict__ aw,
                   const float* __restrict__ ab, const float* __restrict__ eb2,
                   float* __restrict__ wsv, float* __restrict__ svb) {
    const int k = threadIdx.x;
    float s = 0.f;
#pragma unroll
    for (int o = 0; o < 64; o++) s += ew2[k * 64 + o] * aw[o];
    wsv[k] = s;
    float e = wsum(eb2[k] * aw[k]);
    if (k == 0) svb[0] = e + ab[0];
}

// ---- kA: HA[i][k], HB[j][k] ----
__global__ void kA(const float* __restrict__ h, const float* __restrict__ ew1,
                   const float* __restrict__ eb1, float* __restrict__ HA,
                   float* __restrict__ HB) {
    const int i = blockIdx.x, o = threadIdx.x;
    float hv = h[i * 64 + o];
    float a = 0.f, b = eb1[o];
#pragma unroll
    for (int k = 0; k < 64; k++) {
        float hk = __shfl(hv, k, 64);
        a += hk * ew1[k * 64 + o];
        b += hk * ew1[(64 + k) * 64 + o];
    }
    HA[i * 64 + o] = a;
    HB[i * 64 + o] = b;
}

// ---- kBn: pass 1 — ls row via linear sv (no GEMM) + fused softmax stats ----
__global__ __launch_bounds__(256) void kBn(
    const float* __restrict__ x, const float* __restrict__ ew1,
    const float* __restrict__ HA, const float* __restrict__ HB,
    const float* __restrict__ wsv, const float* __restrict__ svb,
    const float* __restrict__ lg, float* __restrict__ ls,
    float* __restrict__ rowm, float* __restrict__ rowd) {
    const int i = blockIdx.x;
    const int t = threadIdx.x;
    const float* HAi = HA + i * 64;       // uniform -> s_load
    const float* w1 = ew1 + 128 * 64;     // uniform
    const float gamma = __expf(lg[0]);
    const float svb0 = svb[0];
    const float xi0 = x[i * 3 + 0], xi1 = x[i * 3 + 1], xi2 = x[i * 3 + 2];

    float le[4], lv[4];
    float me = -3.0e38f, ms = -3.0e38f;
#pragma unroll 1
    for (int q = 0; q < 4; q++) {
        const int j = t + q * 256;
        float dx = xi0 - x[j * 3 + 0];
        float dy = xi1 - x[j * 3 + 1];
        float dz = xi2 - x[j * 3 + 2];
        float nrm = pnorm(dx, dy, dz);
        float d0 = 0.f, d1 = 0.f, d2 = 0.f, d3 = 0.f;
#pragma unroll
        for (int k = 0; k < 64; k += 4) {
            float4 hb = *(const float4*)&HB[j * 64 + k];
            d0 += siluf(HAi[k + 0] + hb.x + nrm * w1[k + 0]) * wsv[k + 0];
            d1 += siluf(HAi[k + 1] + hb.y + nrm * w1[k + 1]) * wsv[k + 1];
            d2 += siluf(HAi[k + 2] + hb.z + nrm * w1[k + 2]) * wsv[k + 2];
            d3 += siluf(HAi[k + 3] + hb.w + nrm * w1[k + 3]) * wsv[k + 3];
        }
        float sv = (d0 + d1) + (d2 + d3) + svb0;
        sv = sv >= 0.f ? sv : 0.01f * sv;
        if (j == i) sv -= BIGINF;
        ls[(size_t)i * NN + j] = sv;
        float l = -(nrm + (i == j ? BIGINF : 0.f)) * gamma;
        le[q] = l; lv[q] = sv;
        me = fmaxf(me, l); ms = fmaxf(ms, sv);
    }
    // fused softmax stats (old kC)
    __shared__ float sm[4], ss[4], s1[4], s2[4], s3[4];
#pragma unroll
    for (int off = 32; off > 0; off >>= 1) {
        me = fmaxf(me, __shfl_xor(me, off, 64));
        ms = fmaxf(ms, __shfl_xor(ms, off, 64));
    }
    const int w = t >> 6;
    if ((t & 63) == 0) { sm[w] = me; ss[w] = ms; }
    __syncthreads();
    me = fmaxf(fmaxf(sm[0], sm[1]), fmaxf(sm[2], sm[3]));
    ms = fmaxf(fmaxf(ss[0], ss[1]), fmaxf(ss[2], ss[3]));
    float Se = 0.f, Ss = 0.f, Sq = 0.f;
#pragma unroll
    for (int q = 0; q < 4; q++) {
        float ee = __expf(le[q] - me);
        float es = __expf(lv[q] - ms);
        Se += ee; Ss += es; Sq += ee * es;
    }
    Se = wsum(Se); Ss = wsum(Ss); Sq = wsum(Sq);
    if ((t & 63) == 0) { s1[w] = Se; s2[w] = Ss; s3[w] = Sq; }
    __syncthreads();
    if (t == 0) {
        rowm[i] = me + ms;
        rowd[i] = (s3[0] + s3[1] + s3[2] + s3[3]) +
                  EPSV * (s1[0] + s1[1] + s1[2] + s1[3]) * (s2[0] + s2[1] + s2[2] + s2[3]);
    }
}

// stage 64-wide bf16 weight rows into LDS stride-LSTR
__device__ __forceinline__ void stageW(const short* __restrict__ g, short* s,
                                       int tid, int rows) {
    for (int c = tid; c < rows * 16; c += 256) {
        int r = c >> 4, q = c & 15;
        *(short4v*)&s[r * LSTR + q * 4] = *(const short4v*)&g[r * 64 + q * 4];
    }
}

__device__ __forceinline__ void gemm64(const short* sA, const short* sB, int w,
                                       int col, int quad, f32x4 acc[4]) {
    const short* ap = &sA[(w * 16 + col) * LSTR + quad * 8];
#pragma unroll
    for (int kb = 0; kb < 2; kb++) {
        short8 a = *(const short8*)&ap[kb * 32];
#pragma unroll
        for (int nb = 0; nb < 4; nb++) {
            short8 b = *(const short8*)&sB[(nb * 16 + col) * LSTR + kb * 32 + quad * 8];
            acc[nb] = __builtin_amdgcn_mfma_f32_16x16x32_bf16(a, b, acc[nb], 0, 0, 0);
        }
    }
}

// ---- kD: pass 2 — he, hagg, phi->xupd, V, coeff->combos ----
__global__ __launch_bounds__(256) void kD(
    const float* __restrict__ x, const float* __restrict__ ew1,
    const float* __restrict__ eb2, const float* __restrict__ cb1,
    const float* __restrict__ cw2, const float* __restrict__ fb1,
    const float* __restrict__ fb2, const float* __restrict__ lg,
    const float* __restrict__ HA, const float* __restrict__ HB,
    const short* __restrict__ ew2T, const short* __restrict__ cw1T,
    const short* __restrict__ fw1T, const short* __restrict__ fw2T,
    const float* __restrict__ ls, const float* __restrict__ rowm,
    const float* __restrict__ rowd, float* __restrict__ hagg,
    float* __restrict__ combos, float* __restrict__ xupd) {
    __shared__ __align__(16) short sU[64 * LSTR];  // U, then wv
    __shared__ __align__(16) short sHe[64 * LSTR];
    __shared__ __align__(16) short sW[64 * LSTR];
    __shared__ float sNrm[64], sFx[64], sFy[64], sFz[64];
    __shared__ float sDx[64], sDy[64], sDz[64], sPh[64];
    __shared__ float sComb[64], sHag[64], sCombos[96];

    const int tid = threadIdx.x;
    const int i = blockIdx.x;
    const int jbase = blockIdx.y * 64;
    const int lane = tid & 63, w = tid >> 6;
    const int col = lane & 15, quad = lane >> 4;

    if (tid < 64) {
        int j = jbase + tid;
        float dx = x[i * 3 + 0] - x[j * 3 + 0];
        float dy = x[i * 3 + 1] - x[j * 3 + 1];
        float dz = x[i * 3 + 2] - x[j * 3 + 2];
        float nrm = pnorm(dx, dy, dz);
        float inv1 = 1.0f / (nrm + 1.0f);
        sNrm[tid] = nrm;
        sDx[tid] = dx; sDy[tid] = dy; sDz[tid] = dz;
        sFx[tid] = dx * inv1; sFy[tid] = dy * inv1; sFz[tid] = dz * inv1;
        float gamma = __expf(lg[0]);
        float le = -(nrm + (j == i ? BIGINF : 0.f)) * gamma;
        sComb[tid] = __expf(le + ls[(size_t)i * NN + j] - rowm[i]) / rowd[i];
        sHag[tid] = 0.f;
    } else if (tid < 160) {
        sCombos[tid - 64] = 0.f;
    }
    stageW(ew2T, sW, tid, 64);
    __syncthreads();

    // U staging (truncating cvt)
    {
        int j = tid >> 2, kc = (tid & 3) * 16;
        float nrm = sNrm[j];
        const float* hb = &HB[(jbase + j) * 64 + kc];
        const float* ha = &HA[i * 64 + kc];
        const float* w1 = &ew1[128 * 64 + kc];
        short8 v0, v1;
#pragma unroll
        for (int t = 0; t < 8; t++) v0[t] = f2bt(siluf(ha[t] + hb[t] + nrm * w1[t]));
#pragma unroll
        for (int t = 0; t < 8; t++) v1[t] = f2bt(siluf(ha[8 + t] + hb[8 + t] + nrm * w1[8 + t]));
        *(short8*)&sU[j * LSTR + kc] = v0;
        *(short8*)&sU[j * LSTR + kc + 8] = v1;
    }
    __syncthreads();

    // GEMM1: he = U@ew2 + eb2 ; hagg partials
    f32x4 acc[4] = {{0.f, 0.f, 0.f, 0.f}, {0.f, 0.f, 0.f, 0.f},
                    {0.f, 0.f, 0.f, 0.f}, {0.f, 0.f, 0.f, 0.f}};
    gemm64(sU, sW, w, col, quad, acc);
    {
        float eb[4];
#pragma unroll
        for (int nb = 0; nb < 4; nb++) eb[nb] = eb2[nb * 16 + col];
        float hv[4][4];
#pragma unroll
        for (int reg = 0; reg < 4; reg++) {
            int row = w * 16 + quad * 4 + reg;
#pragma unroll
            for (int nb = 0; nb < 4; nb++) {
                hv[nb][reg] = acc[nb][reg] + eb[nb];
                sHe[row * LSTR + nb * 16 + col] = f2bt(hv[nb][reg]);
            }
        }
#pragma unroll
        for (int nb = 0; nb < 4; nb++) {
            float v = 0.f;
#pragma unroll
            for (int reg = 0; reg < 4; reg++)
                v += hv[nb][reg] * sComb[w * 16 + quad * 4 + reg];
            v = redquad(v);
            if (quad == 0) atomicAdd(&sHag[nb * 16 + col], v);
        }
    }
    __syncthreads();
    stageW(cw1T, sW, tid, 64);
    __syncthreads();

    // GEMM2 (phi): P = he@cw1; ph = sum silu(P+cb1)*cw2
    {
        f32x4 p[4] = {{0.f, 0.f, 0.f, 0.f}, {0.f, 0.f, 0.f, 0.f},
                      {0.f, 0.f, 0.f, 0.f}, {0.f, 0.f, 0.f, 0.f}};
        gemm64(sHe, sW, w, col, quad, p);
        float cbv[4], cwv[4];
#pragma unroll
        for (int nb = 0; nb < 4; nb++) { cbv[nb] = cb1[nb * 16 + col]; cwv[nb] = cw2[nb * 16 + col]; }
#pragma unroll
        for (int reg = 0; reg < 4; reg++) {
            float ph = 0.f;
#pragma unroll
            for (int nb = 0; nb < 4; nb++) ph += siluf(p[nb][reg] + cbv[nb]) * cwv[nb];
            ph = red16(ph);
            if (col == 0) sPh[w * 16 + quad * 4 + reg] = ph;
        }
    }
    __syncthreads();
    stageW(fw1T, sW, tid, 64);
    __syncthreads();

    // GEMM-V: V = he@fw1; wv = silu(comb*V + fb1) -> sU
    f32x4 vacc[4] = {{0.f, 0.f, 0.f, 0.f}, {0.f, 0.f, 0.f, 0.f},
                     {0.f, 0.f, 0.f, 0.f}, {0.f, 0.f, 0.f, 0.f}};
    gemm64(sHe, sW, w, col, quad, vacc);
    {
        float fbv[4];
#pragma unroll
        for (int nb = 0; nb < 4; nb++) fbv[nb] = fb1[nb * 16 + col];
#pragma unroll
        for (int reg = 0; reg < 4; reg++) {
            int row = w * 16 + quad * 4 + reg;
            float cm = sComb[row];
#pragma unroll
            for (int nb = 0; nb < 4; nb++)
                sU[row * LSTR + nb * 16 + col] = f2bt(siluf(cm * vacc[nb][reg] + fbv[nb]));
        }
    }
    __syncthreads();
    stageW(fw2T, sW, tid, 32);
    __syncthreads();

    // GEMM-C: coeff = wv@fw2 + fb2 (N=32); combos += coeff^T @ dirs
    {
        f32x4 cacc[2] = {{0.f, 0.f, 0.f, 0.f}, {0.f, 0.f, 0.f, 0.f}};
        const short* ap = &sU[(w * 16 + col) * LSTR + quad * 8];
#pragma unroll
        for (int kb = 0; kb < 2; kb++) {
            short8 a = *(const short8*)&ap[kb * 32];
#pragma unroll
            for (int nb = 0; nb < 2; nb++) {
                short8 b = *(const short8*)&sW[(nb * 16 + col) * LSTR + kb * 32 + quad * 8];
                cacc[nb] = __builtin_amdgcn_mfma_f32_16x16x32_bf16(a, b, cacc[nb], 0, 0, 0);
            }
        }
#pragma unroll
        for (int nb = 0; nb < 2; nb++) {
            float fb2v = fb2[nb * 16 + col];
            float px = 0.f, py = 0.f, pz = 0.f;
#pragma unroll
            for (int reg = 0; reg < 4; reg++) {
                int row = w * 16 + quad * 4 + reg;
                float cf = cacc[nb][reg] + fb2v;
                px += cf * sFx[row]; py += cf * sFy[row]; pz += cf * sFz[row];
            }
            px = redquad(px); py = redquad(py); pz = redquad(pz);
            if (quad == 0) {
                int c = nb * 16 + col;
                atomicAdd(&sCombos[c * 3 + 0], px);
                atomicAdd(&sCombos[c * 3 + 1], py);
                atomicAdd(&sCombos[c * 3 + 2], pz);
            }
        }
    }
    __syncthreads();
    if (tid < 64) {
        atomicAdd(&hagg[i * 64 + tid], sHag[tid]);
        float xa0 = wsum(sPh[tid] * sDx[tid]);
        float xa1 = wsum(sPh[tid] * sDy[tid]);
        float xa2 = wsum(sPh[tid] * sDz[tid]);
        if (tid == 0) {
            atomicAdd(&xupd[i * 3 + 0], xa0);
            atomicAdd(&xupd[i * 3 + 1], xa1);
            atomicAdd(&xupd[i * 3 + 2], xa2);
        }
    }
    if (tid < 96) atomicAdd(&combos[i * 96 + tid], sCombos[tid]);
}

// ---- kE: post MLPs + node update + coordinate output (verified) ----
__global__ void kE(const float* __restrict__ h, const float* __restrict__ x,
                   const float* __restrict__ nw1, const float* __restrict__ nb1,
                   const float* __restrict__ nw2, const float* __restrict__ nb2,
                   const float* __restrict__ pw1, const float* __restrict__ pb1,
                   const float* __restrict__ pw2, const float* __restrict__ pb2,
                   const float* __restrict__ hagg, const float* __restrict__ combos,
                   const float* __restrict__ xupd, float* __restrict__ out) {
    const int i = blockIdx.x, o = threadIdx.x;
    const float invN = 1.0f / (float)NN;
    float r = 0.f;
    if (o < 32) {
        float v0 = combos[i * 96 + o * 3 + 0] * invN;
        float v1 = combos[i * 96 + o * 3 + 1] * invN;
        float v2 = combos[i * 96 + o * 3 + 2] * invN;
        r = v0 * v0 + v1 * v1 + v2 * v2;
    }
    float t1 = pb1[o];
#pragma unroll
    for (int k = 0; k < 32; k++) t1 += __shfl(r, k, 64) * pw1[k * 64 + o];
    t1 = siluf(t1);
    float hc = pb2[o];
#pragma unroll
    for (int k = 0; k < 64; k++) hc += __shfl(t1, k, 64) * pw2[k * 64 + o];
    float hi = h[i * 64 + o];
    float ha = hagg[i * 64 + o];
    float t2 = nb1[o];
#pragma unroll
    for (int k = 0; k < 64; k++) t2 += __shfl(hi, k, 64) * nw1[k * 64 + o];
#pragma unroll
    for (int k = 0; k < 64; k++) t2 += __shfl(ha, k, 64) * nw1[(64 + k) * 64 + o];
#pragma unroll
    for (int k = 0; k < 64; k++) t2 += __shfl(hc, k, 64) * nw1[(128 + k) * 64 + o];
    t2 = siluf(t2);
    float ho = hi + nb2[o];
#pragma unroll
    for (int k = 0; k < 64; k++) ho += __shfl(t2, k, 64) * nw2[k * 64 + o];
    out[i * 64 + o] = ho;
    if (o < 3)
        out[NN * 64 + i * 3 + o] = x[i * 3 + o] + xupd[i * 3 + o] * invN;
}

extern "C" void kernel_launch(void* const* d_in, const int* in_sizes, int n_in,
                              void* d_out, int out_size, void* d_ws, size_t ws_size,
                              hipStream_t stream) {
    (void)in_sizes; (void)n_in; (void)out_size; (void)ws_size;
    const float* h   = (const float*)d_in[0];
    const float* x   = (const float*)d_in[1];
    const float* ew1 = (const float*)d_in[2];
    const float* eb1 = (const float*)d_in[3];
    const float* ew2 = (const float*)d_in[4];
    const float* eb2 = (const float*)d_in[5];
    const float* nw1 = (const float*)d_in[6];
    const float* nb1 = (const float*)d_in[7];
    const float* nw2 = (const float*)d_in[8];
    const float* nb2 = (const float*)d_in[9];
    const float* cw1 = (const float*)d_in[10];
    const float* cb1 = (const float*)d_in[11];
    const float* cw2 = (const float*)d_in[12];
    const float* aw  = (const float*)d_in[13];
    const float* ab  = (const float*)d_in[14];
    const float* fw1 = (const float*)d_in[15];
    const float* fb1 = (const float*)d_in[16];
    const float* fw2 = (const float*)d_in[17];
    const float* fb2 = (const float*)d_in[18];
    const float* pw1 = (const float*)d_in[19];
    const float* pb1 = (const float*)d_in[20];
    const float* pw2 = (const float*)d_in[21];
    const float* pb2 = (const float*)d_in[22];
    const float* lg  = (const float*)d_in[23];
    float* out = (float*)d_out;

    float* W      = (float*)d_ws;
    float* ls     = W;                        // N*N
    float* HA     = ls + (size_t)NN * NN;     // N*64
    float* HB     = HA + NN * 64;             // N*64
    float* rowm   = HB + NN * 64;             // N
    float* rowd   = rowm + NN;                // N
    float* hagg   = rowd + NN;                // N*64   (atomic acc)
    float* combos = hagg + NN * 64;           // N*96   (atomic acc)
    float* xupd   = combos + NN * 96;         // N*3    (atomic acc)
    float* wsv    = xupd + NN * 3;            // 64
    float* svb    = wsv + 64;                 // 1
    short* ew2T   = (short*)(svb + 4);        // 64*64 bf16
    short* cw1T   = ew2T + 64 * 64;
    short* fw1T   = cw1T + 64 * 64;
    short* fw2T   = fw1T + 64 * 64;           // 32*64 bf16

    hipMemsetAsync(hagg, 0, (size_t)(NN * 64 + NN * 96 + NN * 3) * sizeof(float), stream);
    kT<<<64, 64, 0, stream>>>(ew2, cw1, fw1, fw2, ew2T, cw1T, fw1T, fw2T);
    kP<<<1, 64, 0, stream>>>(ew2, aw, ab, eb2, wsv, svb);
    kA<<<NN, 64, 0, stream>>>(h, ew1, eb1, HA, HB);
    kBn<<<NN, 256, 0, stream>>>(x, ew1, HA, HB, wsv, svb, lg, ls, rowm, rowd);
    dim3 g2(NN, NN / 64);
    kD<<<g2, 256, 0, stream>>>(x, ew1, eb2, cb1, cw2, fb1, fb2, lg, HA, HB,
                               ew2T, cw1T, fw1T, fw2T, ls, rowm, rowd,
                               hagg, combos, xupd);
    kE<<<NN, 64, 0, stream>>>(h, x, nw1, nb1, nw2, nb2, pw1, pb1, pw2, pb2,
                              hagg, combos, xupd, out);
}